// Round 10
// baseline (165.075 us; speedup 1.0000x reference)
//
#include <hip/hip_runtime.h>

typedef float f4 __attribute__((ext_vector_type(4)));

#define BB 1024
#define SS 192
#define DD 512
#define NUM_LAYERS 3
#define LN_EPS 1e-5f
#define NROWS (BB * SS)
#define FUSED_BLOCKS 2048
#define NWAVES (FUSED_BLOCKS * 4)

// Merged prep:
//  blocks [0, SS)      : add_tab[pos] = item_pos[pos/3] + layer[pos%3] + decay[pos/3]
//  blocks [SS, SS+256) : start[b] via ballot; start=SS if row has no content
__global__ __launch_bounds__(256) void prep_kernel(
    const int* __restrict__ mask,
    const float* __restrict__ item_pos,
    const float* __restrict__ layer_emb,
    const float* __restrict__ decay,
    float* __restrict__ add_tab,
    int* __restrict__ start)
{
    if (blockIdx.x < SS) {
        const int p = blockIdx.x;
        const int t = threadIdx.x;
        if (t < DD / 4) {
            const int item = p / NUM_LAYERS;
            const int layer = p - item * NUM_LAYERS;
            const f4 iv = reinterpret_cast<const f4*>(item_pos + item * DD)[t];
            const f4 lv = reinterpret_cast<const f4*>(layer_emb + layer * DD)[t];
            const f4 dv = reinterpret_cast<const f4*>(decay + item * DD)[t];
            reinterpret_cast<f4*>(add_tab + p * DD)[t] = iv + lv + dv;
        }
    } else {
        const int b = (blockIdx.x - SS) * 4 + (threadIdx.x >> 6);
        const int lane = threadIdx.x & 63;
        if (b < BB) {
            const int* m = mask + b * SS;
            const unsigned long long b0 = __ballot(m[lane] > 0);
            const unsigned long long b1 = __ballot(m[lane + 64] > 0);
            const unsigned long long b2 = __ballot(m[lane + 128] > 0);
            int idx;
            if (b0)      idx = __ffsll(b0) - 1;
            else if (b1) idx = 64 + __ffsll(b1) - 1;
            else if (b2) idx = 128 + __ffsll(b2) - 1;
            else         idx = SS;
            if (lane == 0) start[b] = idx;
        }
    }
}

template <int CTRL>
__device__ __forceinline__ float dpp_x(float v) {
    return __uint_as_float((unsigned)__builtin_amdgcn_update_dpp(
            0, (int)__float_as_uint(v), CTRL, 0xF, 0xF, true));
}
__device__ __forceinline__ float swz16(float v) {
    return __uint_as_float((unsigned)__builtin_amdgcn_ds_swizzle(
            (int)__float_as_uint(v), 0x401f));
}
__device__ __forceinline__ float bper32(float v, int xaddr32) {
    return __uint_as_float((unsigned)__builtin_amdgcn_ds_bpermute(
            xaddr32, (int)__float_as_uint(v)));
}

// 2 interleaved wave64 all-reduces (sum, sumsq): DPP levels are VALU-latency,
// final 2 levels via xor16 swizzle + cross-32 bpermute.
__device__ __forceinline__ void wave_allreduce2(float& v0, float& v1, int xaddr32) {
    v0 += dpp_x<0xB1>(v0);  v1 += dpp_x<0xB1>(v1);    // xor1
    v0 += dpp_x<0x4E>(v0);  v1 += dpp_x<0x4E>(v1);    // xor2
    v0 += dpp_x<0x141>(v0); v1 += dpp_x<0x141>(v1);   // row_half_mirror
    v0 += dpp_x<0x140>(v0); v1 += dpp_x<0x140>(v1);   // row_mirror
    v0 += swz16(v0);        v1 += swz16(v1);          // xor16
    v0 += bper32(v0, xaddr32); v1 += bper32(v1, xaddr32); // xor32
}

// DENSE streaming version: every row is read, enhanced, normalized, and the
// result multiplied by keep (0 for padded rows) -- branch-free, no load gating,
// pure dense read+write streams. Tests the read-stream-density hypothesis.
__global__ __launch_bounds__(256) void fused_kernel(
    const float* __restrict__ tok,
    const float* __restrict__ add_tab,
    const float* __restrict__ lnw,
    const float* __restrict__ lnb,
    const int* __restrict__ start,
    float* __restrict__ out)
{
    const int wid = threadIdx.x >> 6;
    const int lane = threadIdx.x & 63;
    const int l0 = lane;
    const int l1 = lane + 64;
    const int xaddr32 = (lane ^ 32) << 2;

    const f4 w0 = reinterpret_cast<const f4*>(lnw)[l0];
    const f4 w1 = reinterpret_cast<const f4*>(lnw)[l1];
    const f4 c0 = reinterpret_cast<const f4*>(lnb)[l0];
    const f4 c1 = reinterpret_cast<const f4*>(lnb)[l1];

    const int wave = blockIdx.x * 4 + wid;

    #pragma unroll 1
    for (int row = wave; row < NROWS; row += NWAVES) {
        const int b = row / SS;
        const int s = row - b * SS;
        const int st = start[b];                  // 4KB array, L1-resident
        const int pos = s - st;
        const int posc = pos < 0 ? 0 : pos;       // clamp for the gather
        const float keep = pos < 0 ? 0.0f : 1.0f; // wave-uniform

        // dense, unconditional loads
        const f4* x4 = reinterpret_cast<const f4*>(tok + (size_t)row * DD);
        const f4 xv0 = x4[l0];
        const f4 xv1 = x4[l1];

        const f4* a4 = reinterpret_cast<const f4*>(add_tab + posc * DD);
        const f4 y0 = xv0 + a4[l0];
        const f4 y1 = xv1 + a4[l1];

        float sum = (y0.x + y0.y) + (y0.z + y0.w)
                  + (y1.x + y1.y) + (y1.z + y1.w);
        const f4 q0 = y0 * y0;
        const f4 q1 = y1 * y1;
        float sq = (q0.x + q0.y) + (q0.z + q0.w)
                 + (q1.x + q1.y) + (q1.z + q1.w);

        wave_allreduce2(sum, sq, xaddr32);

        const float mu  = sum * (1.0f / DD);
        const float var = sq * (1.0f / DD) - mu * mu;
        const float inv = rsqrtf(var + LN_EPS) * keep;   // fold mask into scale
        const float cb  = keep;                          // bias also masked

        f4* o4 = reinterpret_cast<f4*>(out + (size_t)row * DD);
        o4[l0] = (y0 - mu) * inv * w0 + c0 * cb;
        o4[l1] = (y1 - mu) * inv * w1 + c1 * cb;
    }
}

extern "C" void kernel_launch(void* const* d_in, const int* in_sizes, int n_in,
                              void* d_out, int out_size, void* d_ws, size_t ws_size,
                              hipStream_t stream) {
    const float* tok       = (const float*)d_in[0];   // (B,S,D)
    const int*   mask      = (const int*)d_in[1];     // (B,S)
    const float* item_pos  = (const float*)d_in[2];   // (64,D)
    const float* layer_emb = (const float*)d_in[3];   // (3,D)
    const float* decay     = (const float*)d_in[4];   // (64,D)
    const float* lnw       = (const float*)d_in[5];   // (D,)
    const float* lnb       = (const float*)d_in[6];   // (D,)
    float* out = (float*)d_out;

    // workspace layout: [ add_tab: SS*DD floats ][ start: BB ints ]
    float* add_tab = (float*)d_ws;
    int* start = (int*)((char*)d_ws + (size_t)SS * DD * sizeof(float));

    prep_kernel<<<SS + 256, 256, 0, stream>>>(mask, item_pos, layer_emb, decay,
                                              add_tab, start);
    fused_kernel<<<FUSED_BLOCKS, 256, 0, stream>>>(tok, add_tab, lnw, lnb, start, out);
}

// Round 11
// 150.776 us; speedup vs baseline: 1.0948x; 1.0948x over previous
//
#include <hip/hip_runtime.h>

typedef float f4 __attribute__((ext_vector_type(4)));

#define BB 1024
#define SS 192
#define DD 512
#define NUM_LAYERS 3
#define LN_EPS 1e-5f
#define NROWS (BB * SS)
#define ZERO_BLOCKS 512
#define CONT_BLOCKS 2048
#define MAIN_BLOCKS (ZERO_BLOCKS + CONT_BLOCKS)
#define CONT_WAVES (CONT_BLOCKS * 4)

// ---------------- prep: add_tab + start[] + compact content-row list --------
// blocks [0, SS)        : add_tab[pos] = item_pos[pos/3] + layer[pos%3] + decay[pos/3]
// blocks [SS, SS+BB)    : one block per b: ballot -> start[b]; reserve space in
//                         the compact list via atomicAdd (per-b count padded to
//                         even) and write packed entries (row<<8 | pos).
__global__ __launch_bounds__(256) void prep_kernel(
    const int* __restrict__ mask,
    const float* __restrict__ item_pos,
    const float* __restrict__ layer_emb,
    const float* __restrict__ decay,
    float* __restrict__ add_tab,
    int* __restrict__ start,
    int* __restrict__ list,
    int* __restrict__ nc)
{
    const int tid = threadIdx.x;
    if (blockIdx.x < SS) {
        const int p = blockIdx.x;
        if (tid < DD / 4) {
            const int item = p / NUM_LAYERS;
            const int layer = p - item * NUM_LAYERS;
            const f4 iv = reinterpret_cast<const f4*>(item_pos + item * DD)[tid];
            const f4 lv = reinterpret_cast<const f4*>(layer_emb + layer * DD)[tid];
            const f4 dv = reinterpret_cast<const f4*>(decay + item * DD)[tid];
            reinterpret_cast<f4*>(add_tab + p * DD)[tid] = iv + lv + dv;
        }
        return;
    }

    const int b = blockIdx.x - SS;
    const int lane = tid & 63;
    const int* m = mask + b * SS;
    // every wave computes the same ballot (no inter-wave comm needed)
    const unsigned long long b0 = __ballot(m[lane] > 0);
    const unsigned long long b1 = __ballot(m[lane + 64] > 0);
    const unsigned long long b2 = __ballot(m[lane + 128] > 0);
    int st;
    if (b0)      st = __ffsll(b0) - 1;
    else if (b1) st = 64 + __ffsll(b1) - 1;
    else if (b2) st = 128 + __ffsll(b2) - 1;
    else         st = SS;

    const int cnt = SS - st;                 // >= 1 by construction of inputs
    const int cntp = cnt + (cnt & 1);        // pad to even: pairs stay in-b

    __shared__ int sh_o;
    if (tid == 0) {
        start[b] = st;
        sh_o = atomicAdd(nc, cntp);
    }
    __syncthreads();
    const int o = sh_o;

    for (int j = tid; j < cntp; j += 256) {
        const int jj = j < cnt ? j : cnt - 1;        // duplicate last if odd
        list[o + j] = ((b * SS + st + jj) << 8) | jj;
    }
}

template <int CTRL>
__device__ __forceinline__ float dpp_x(float v) {
    return __uint_as_float((unsigned)__builtin_amdgcn_update_dpp(
            0, (int)__float_as_uint(v), CTRL, 0xF, 0xF, true));
}
__device__ __forceinline__ float swz16(float v) {
    return __uint_as_float((unsigned)__builtin_amdgcn_ds_swizzle(
            (int)__float_as_uint(v), 0x401f));
}
__device__ __forceinline__ float bper32(float v, int xaddr32) {
    return __uint_as_float((unsigned)__builtin_amdgcn_ds_bpermute(
            xaddr32, (int)__float_as_uint(v)));
}

// 4 interleaved wave64 all-reduces (independent per level -> ILP).
__device__ __forceinline__ void wave_allreduce4(
    float& v0, float& v1, float& v2, float& v3, int xaddr32)
{
    v0 += dpp_x<0xB1>(v0);  v1 += dpp_x<0xB1>(v1);
    v2 += dpp_x<0xB1>(v2);  v3 += dpp_x<0xB1>(v3);
    v0 += dpp_x<0x4E>(v0);  v1 += dpp_x<0x4E>(v1);
    v2 += dpp_x<0x4E>(v2);  v3 += dpp_x<0x4E>(v3);
    v0 += dpp_x<0x141>(v0); v1 += dpp_x<0x141>(v1);
    v2 += dpp_x<0x141>(v2); v3 += dpp_x<0x141>(v3);
    v0 += dpp_x<0x140>(v0); v1 += dpp_x<0x140>(v1);
    v2 += dpp_x<0x140>(v2); v3 += dpp_x<0x140>(v3);
    v0 += swz16(v0); v1 += swz16(v1); v2 += swz16(v2); v3 += swz16(v3);
    v0 += bper32(v0, xaddr32); v1 += bper32(v1, xaddr32);
    v2 += bper32(v2, xaddr32); v3 += bper32(v3, xaddr32);
}

// ---------------- main: zerofill blocks + branch-free compacted content -----
__global__ __launch_bounds__(256) void main_kernel(
    const float* __restrict__ tok,
    const float* __restrict__ add_tab,
    const float* __restrict__ lnw,
    const float* __restrict__ lnb,
    const int* __restrict__ start,
    const int* __restrict__ list,
    const int* __restrict__ nc,
    float* __restrict__ out)
{
    const int tid = threadIdx.x;

    if (blockIdx.x < ZERO_BLOCKS) {
        // pure write burst: zero the padded prefix of 2 batch rows
        const f4 z = {0.f, 0.f, 0.f, 0.f};
        #pragma unroll
        for (int q = 0; q < 2; ++q) {
            const int b = blockIdx.x * 2 + q;
            const int st = start[b];
            f4* o4 = reinterpret_cast<f4*>(out + (size_t)b * SS * DD);
            const int nf4 = st * (DD / 4);
            for (int i = tid; i < nf4; i += 256)
                o4[i] = z;
        }
        return;
    }

    // content: grid-stride over PAIRS of compacted entries; no branches,
    // no start[] loads, unconditional loads, 4KB contiguous runs.
    const int wid = tid >> 6;
    const int lane = tid & 63;
    const int l0 = lane;
    const int l1 = lane + 64;
    const int xaddr32 = (lane ^ 32) << 2;

    const f4 w0 = reinterpret_cast<const f4*>(lnw)[l0];
    const f4 w1 = reinterpret_cast<const f4*>(lnw)[l1];
    const f4 c0 = reinterpret_cast<const f4*>(lnb)[l0];
    const f4 c1 = reinterpret_cast<const f4*>(lnb)[l1];

    const int np = *nc >> 1;                         // pairs (nc is even)
    const int2* list2 = reinterpret_cast<const int2*>(list);
    const int wave = (blockIdx.x - ZERO_BLOCKS) * 4 + wid;

    #pragma unroll 1
    for (int i = wave; i < np; i += CONT_WAVES) {
        const int2 e = list2[i];
        const int r0 = e.x >> 8, p0 = e.x & 255;
        const int r1 = e.y >> 8, p1 = e.y & 255;

        const f4* xa = reinterpret_cast<const f4*>(tok + (size_t)r0 * DD);
        const f4* xb = reinterpret_cast<const f4*>(tok + (size_t)r1 * DD);
        const f4 x00 = xa[l0], x01 = xa[l1];
        const f4 x10 = xb[l0], x11 = xb[l1];

        const f4* aa = reinterpret_cast<const f4*>(add_tab + p0 * DD);
        const f4* ab = reinterpret_cast<const f4*>(add_tab + p1 * DD);
        const f4 y00 = x00 + aa[l0], y01 = x01 + aa[l1];
        const f4 y10 = x10 + ab[l0], y11 = x11 + ab[l1];

        float sumA = (y00.x + y00.y) + (y00.z + y00.w)
                   + (y01.x + y01.y) + (y01.z + y01.w);
        const f4 qa0 = y00 * y00, qa1 = y01 * y01;
        float sqA = (qa0.x + qa0.y) + (qa0.z + qa0.w)
                  + (qa1.x + qa1.y) + (qa1.z + qa1.w);

        float sumB = (y10.x + y10.y) + (y10.z + y10.w)
                   + (y11.x + y11.y) + (y11.z + y11.w);
        const f4 qb0 = y10 * y10, qb1 = y11 * y11;
        float sqB = (qb0.x + qb0.y) + (qb0.z + qb0.w)
                  + (qb1.x + qb1.y) + (qb1.z + qb1.w);

        wave_allreduce4(sumA, sqA, sumB, sqB, xaddr32);

        const float muA  = sumA * (1.0f / DD);
        const float invA = rsqrtf(sqA * (1.0f / DD) - muA * muA + LN_EPS);
        const float muB  = sumB * (1.0f / DD);
        const float invB = rsqrtf(sqB * (1.0f / DD) - muB * muB + LN_EPS);

        f4* oa = reinterpret_cast<f4*>(out + (size_t)r0 * DD);
        f4* ob = reinterpret_cast<f4*>(out + (size_t)r1 * DD);
        oa[l0] = (y00 - muA) * invA * w0 + c0;
        oa[l1] = (y01 - muA) * invA * w1 + c1;
        ob[l0] = (y10 - muB) * invB * w0 + c0;
        ob[l1] = (y11 - muB) * invB * w1 + c1;
    }
}

extern "C" void kernel_launch(void* const* d_in, const int* in_sizes, int n_in,
                              void* d_out, int out_size, void* d_ws, size_t ws_size,
                              hipStream_t stream) {
    const float* tok       = (const float*)d_in[0];   // (B,S,D)
    const int*   mask      = (const int*)d_in[1];     // (B,S)
    const float* item_pos  = (const float*)d_in[2];   // (64,D)
    const float* layer_emb = (const float*)d_in[3];   // (3,D)
    const float* decay     = (const float*)d_in[4];   // (64,D)
    const float* lnw       = (const float*)d_in[5];   // (D,)
    const float* lnb       = (const float*)d_in[6];   // (D,)
    float* out = (float*)d_out;

    // workspace: [nc:int pad to 256B][add_tab SS*DD f32][start BB int][list]
    int*   nc      = (int*)d_ws;
    float* add_tab = (float*)((char*)d_ws + 256);
    int*   start   = (int*)((char*)add_tab + (size_t)SS * DD * sizeof(float));
    int*   list    = (int*)((char*)start + BB * sizeof(int));

    hipMemsetAsync(nc, 0, sizeof(int), stream);
    prep_kernel<<<SS + BB, 256, 0, stream>>>(mask, item_pos, layer_emb, decay,
                                             add_tab, start, list, nc);
    main_kernel<<<MAIN_BLOCKS, 256, 0, stream>>>(tok, add_tab, lnw, lnb,
                                                 start, list, nc, out);
}

// Round 12
// 144.079 us; speedup vs baseline: 1.1457x; 1.0465x over previous
//
#include <hip/hip_runtime.h>

typedef float f4 __attribute__((ext_vector_type(4)));

#define BB 1024
#define SS 192
#define DD 512
#define NUM_LAYERS 3
#define LN_EPS 1e-5f
#define ZERO_BLOCKS 512
#define CONT_BLOCKS 2048
#define MAIN_BLOCKS (ZERO_BLOCKS + CONT_BLOCKS)
#define CONT_WAVES (CONT_BLOCKS * 4)

// ---------------- prep: add_tab + start[] --------------------------------
__global__ __launch_bounds__(256) void prep_kernel(
    const int* __restrict__ mask,
    const float* __restrict__ item_pos,
    const float* __restrict__ layer_emb,
    const float* __restrict__ decay,
    float* __restrict__ add_tab,
    int* __restrict__ start)
{
    const int tid = threadIdx.x;
    if (blockIdx.x < SS) {
        const int p = blockIdx.x;
        if (tid < DD / 4) {
            const int item = p / NUM_LAYERS;
            const int layer = p - item * NUM_LAYERS;
            const f4 iv = reinterpret_cast<const f4*>(item_pos + item * DD)[tid];
            const f4 lv = reinterpret_cast<const f4*>(layer_emb + layer * DD)[tid];
            const f4 dv = reinterpret_cast<const f4*>(decay + item * DD)[tid];
            reinterpret_cast<f4*>(add_tab + p * DD)[tid] = iv + lv + dv;
        }
        return;
    }
    const int b = (blockIdx.x - SS) * 4 + (tid >> 6);
    const int lane = tid & 63;
    if (b < BB) {
        const int* m = mask + b * SS;
        const unsigned long long b0 = __ballot(m[lane] > 0);
        const unsigned long long b1 = __ballot(m[lane + 64] > 0);
        const unsigned long long b2 = __ballot(m[lane + 128] > 0);
        int idx;
        if (b0)      idx = __ffsll(b0) - 1;
        else if (b1) idx = 64 + __ffsll(b1) - 1;
        else if (b2) idx = 128 + __ffsll(b2) - 1;
        else         idx = SS;
        if (lane == 0) start[b] = idx;
    }
}

// ---------------- scan: exclusive prefix sum of content counts ------------
// P[b] = sum_{j<b} (SS - start[j]); P[BB] = total; nc = total.
__global__ __launch_bounds__(1024) void scan_kernel(
    const int* __restrict__ start, int* __restrict__ P, int* __restrict__ nc)
{
    __shared__ int sh[1024];
    const int t = threadIdx.x;
    const int cnt = SS - start[t];
    sh[t] = cnt;
    __syncthreads();
    #pragma unroll
    for (int off = 1; off < 1024; off <<= 1) {
        const int u = (t >= off) ? sh[t - off] : 0;
        __syncthreads();
        sh[t] += u;
        __syncthreads();
    }
    P[t] = sh[t] - cnt;                 // exclusive
    if (t == 1023) { P[1024] = sh[1023]; *nc = sh[1023]; }
}

template <int CTRL>
__device__ __forceinline__ float dpp_x(float v) {
    return __uint_as_float((unsigned)__builtin_amdgcn_update_dpp(
            0, (int)__float_as_uint(v), CTRL, 0xF, 0xF, true));
}
__device__ __forceinline__ float swz16(float v) {
    return __uint_as_float((unsigned)__builtin_amdgcn_ds_swizzle(
            (int)__float_as_uint(v), 0x401f));
}
__device__ __forceinline__ float bper32(float v, int xaddr32) {
    return __uint_as_float((unsigned)__builtin_amdgcn_ds_bpermute(
            xaddr32, (int)__float_as_uint(v)));
}

__device__ __forceinline__ void wave_allreduce2(float& v0, float& v1, int xaddr32) {
    v0 += dpp_x<0xB1>(v0);  v1 += dpp_x<0xB1>(v1);
    v0 += dpp_x<0x4E>(v0);  v1 += dpp_x<0x4E>(v1);
    v0 += dpp_x<0x141>(v0); v1 += dpp_x<0x141>(v1);
    v0 += dpp_x<0x140>(v0); v1 += dpp_x<0x140>(v1);
    v0 += swz16(v0);        v1 += swz16(v1);
    v0 += bper32(v0, xaddr32); v1 += bper32(v1, xaddr32);
}

// ---------------- main: zerofill + address-ordered contiguous windows -----
__global__ __launch_bounds__(256) void main_kernel(
    const float* __restrict__ tok,
    const float* __restrict__ add_tab,
    const float* __restrict__ lnw,
    const float* __restrict__ lnb,
    const int* __restrict__ start,
    const int* __restrict__ P,
    const int* __restrict__ nc,
    float* __restrict__ out)
{
    const int tid = threadIdx.x;

    if (blockIdx.x < ZERO_BLOCKS) {
        const f4 z = {0.f, 0.f, 0.f, 0.f};
        #pragma unroll
        for (int q = 0; q < 2; ++q) {
            const int b = blockIdx.x * 2 + q;
            const int st = start[b];
            f4* o4 = reinterpret_cast<f4*>(out + (size_t)b * SS * DD);
            const int nf4 = st * (DD / 4);
            for (int i = tid; i < nf4; i += 256)
                o4[i] = z;
        }
        return;
    }

    const int wid = tid >> 6;
    const int lane = tid & 63;
    const int l0 = lane;
    const int l1 = lane + 64;
    const int xaddr32 = (lane ^ 32) << 2;

    const f4 w0 = reinterpret_cast<const f4*>(lnw)[l0];
    const f4 w1 = reinterpret_cast<const f4*>(lnw)[l1];
    const f4 c0 = reinterpret_cast<const f4*>(lnb)[l0];
    const f4 c1 = reinterpret_cast<const f4*>(lnb)[l1];

    const int wave = (blockIdx.x - ZERO_BLOCKS) * 4 + wid;
    const int Nc = *nc;
    const int nq = (Nc + CONT_WAVES - 1) / CONT_WAVES;   // rows per wave
    const int gs = wave * nq;
    if (gs >= Nc) return;
    const int ge = (gs + nq < Nc) ? gs + nq : Nc;

    // binary search: largest b with P[b] <= gs (P[0]=0 guarantees validity)
    int lo = 0, hi = BB;
    while (lo < hi) {
        const int mid = (lo + hi + 1) >> 1;
        if (P[mid] <= gs) lo = mid; else hi = mid - 1;
    }
    int b = lo;
    int pb = P[b], pb1 = P[b + 1];

    #pragma unroll 1
    for (int g = gs; g < ge; ++g) {
        if (g >= pb1) {                          // advance batch (wave-uniform)
            do { ++b; pb1 = P[b + 1]; } while (g >= pb1);
            pb = P[b];
        }
        const int pos = g - pb;                  // content-relative position
        const int st = SS - (pb1 - pb);
        const int row = b * SS + st + pos;       // consecutive g -> consecutive row

        const f4* x4 = reinterpret_cast<const f4*>(tok + (size_t)row * DD);
        const f4 xv0 = x4[l0];
        const f4 xv1 = x4[l1];

        const f4* a4 = reinterpret_cast<const f4*>(add_tab + pos * DD);
        const f4 y0 = xv0 + a4[l0];
        const f4 y1 = xv1 + a4[l1];

        float sum = (y0.x + y0.y) + (y0.z + y0.w)
                  + (y1.x + y1.y) + (y1.z + y1.w);
        const f4 q0 = y0 * y0;
        const f4 q1 = y1 * y1;
        float sq = (q0.x + q0.y) + (q0.z + q0.w)
                 + (q1.x + q1.y) + (q1.z + q1.w);

        wave_allreduce2(sum, sq, xaddr32);

        const float mu  = sum * (1.0f / DD);
        const float var = sq * (1.0f / DD) - mu * mu;
        const float inv = rsqrtf(var + LN_EPS);

        f4* o4 = reinterpret_cast<f4*>(out + (size_t)row * DD);
        o4[l0] = (y0 - mu) * inv * w0 + c0;
        o4[l1] = (y1 - mu) * inv * w1 + c1;
    }
}

extern "C" void kernel_launch(void* const* d_in, const int* in_sizes, int n_in,
                              void* d_out, int out_size, void* d_ws, size_t ws_size,
                              hipStream_t stream) {
    const float* tok       = (const float*)d_in[0];   // (B,S,D)
    const int*   mask      = (const int*)d_in[1];     // (B,S)
    const float* item_pos  = (const float*)d_in[2];   // (64,D)
    const float* layer_emb = (const float*)d_in[3];   // (3,D)
    const float* decay     = (const float*)d_in[4];   // (64,D)
    const float* lnw       = (const float*)d_in[5];   // (D,)
    const float* lnb       = (const float*)d_in[6];   // (D,)
    float* out = (float*)d_out;

    // workspace: [nc pad 256B][add_tab SS*DD f32][start BB int][P BB+1 int]
    int*   nc      = (int*)d_ws;
    float* add_tab = (float*)((char*)d_ws + 256);
    int*   start   = (int*)((char*)add_tab + (size_t)SS * DD * sizeof(float));
    int*   P       = (int*)((char*)start + BB * sizeof(int));

    prep_kernel<<<SS + 256, 256, 0, stream>>>(mask, item_pos, layer_emb, decay,
                                              add_tab, start);
    scan_kernel<<<1, 1024, 0, stream>>>(start, P, nc);
    main_kernel<<<MAIN_BLOCKS, 256, 0, stream>>>(tok, add_tab, lnw, lnb,
                                                 start, P, nc, out);
}